// Round 2
// baseline (301.575 us; speedup 1.0000x reference)
//
#include <hip/hip_runtime.h>

// DecayModel: out[b,i,h] = (fwd[i] + bwd[i]) / norm[i], decay = 0.5
//   fwd[i] = sum_{k<=i} 0.5^{i-k} x[k],  bwd[i] = sum_{k>=i} 0.5^{k-i} x[k]
//   norm[i] = 4 - 2^{-i} - 2^{-(S-1-i)}   (== 4.0f exactly for interior i)
//
// R7 -> R8: trade ILP for TLP. R7's counters: 85us, 2.5 TB/s, VALUBusy 5.7%,
// occupancy 9%, VGPR=128. The compiler allocated only 128 VGPRs for a
// pipeline that needs ~240 of live state -> it sank the prefetch loads to
// their uses, so each wave had ~1 load batch in flight and stalled on
// waitcnt ~94% of the time (4 B/cyc/CU vs the 10.25 needed for peak).
// Instead of fighting the scheduler for per-wave ILP, hide latency with
// waves: flat tile-per-block (C=32 rows + K=12 halo each side), 256 threads
// = full H row, 1024 blocks -> 4 blocks/CU, 16 waves/CU (4x R7).
// __launch_bounds__(256,4) pins VGPR<=128 so all 4 blocks stay resident.
// Halo amplification 1.75x is L3-absorbed (R7 FETCH=77MB < 128MB input
// proves input is L3-resident); bijective XCD swizzle groups adjacent
// chunks (which share halos) onto the same XCD L2.

constexpr int B = 16;
constexpr int S = 2048;
constexpr int H = 1024;
constexpr int HV = H / 4;        // 256 v4f per row
constexpr int C = 32;            // tile rows per block
constexpr int K = 12;            // halo taps: 0.5^13 * 6sigma ~ 7e-4 << tol
constexpr int THREADS = 256;     // 4 waves; each thread owns one v4f column
constexpr int NCH = S / C;       // 64 chunks
constexpr int NBLK = NCH * B;    // 1024 blocks
constexpr int NXCD = 8;

typedef float v4f __attribute__((ext_vector_type(4)));

__global__ __launch_bounds__(THREADS, 4) void decay_kernel(
    const v4f* __restrict__ x, v4f* __restrict__ out) {
    // Bijective XCD swizzle (NBLK % 8 == 0): round-robin XCD assignment
    // gets a contiguous range of work items -> adjacent chunks (sharing
    // 12-row halos) hit the same XCD L2.
    const int bid = blockIdx.x;
    const int swz = (bid % NXCD) * (NBLK / NXCD) + bid / NXCD;
    const int chunk = swz % NCH;
    const int b = swz / NCH;
    const int s0 = chunk * C;

    const size_t colBase = (size_t)b * S * HV + threadIdx.x;
    const v4f* __restrict__ xp = x + colBase;   // xp[s*HV] = x[b, s, col]
    v4f* __restrict__ op = out + colBase;

    // ---- issue all 56 row loads up front (source order; compiler keeps
    //      as many in flight as its 128-VGPR budget allows, TLP covers
    //      the rest) ----
    v4f xl[K], xa[C], xr[K];
#pragma unroll
    for (int r = 0; r < K; ++r) {
        const int s = s0 - K + r;
        xl[r] = xp[(size_t)(s < 0 ? 0 : s) * HV];
    }
#pragma unroll
    for (int r = 0; r < C; ++r) xa[r] = xp[(size_t)(s0 + r) * HV];
#pragma unroll
    for (int r = 0; r < K; ++r) {
        const int s = s0 + C + r;
        xr[r] = xp[(size_t)(s > S - 1 ? S - 1 : s) * HV];
    }
    // zero out-of-range halo rows (wave-uniform; only first/last chunks)
    if (chunk == 0) {
#pragma unroll
        for (int r = 0; r < K; ++r) xl[r] = (v4f)0.0f;
    }
    if (chunk == NCH - 1) {
#pragma unroll
        for (int r = 0; r < K; ++r) xr[r] = (v4f)0.0f;
    }

    // ---- forward recurrence (K-tap truncated carry-in, exact in tile) ----
    v4f facc = (v4f)0.0f;
#pragma unroll
    for (int r = 0; r < K; ++r) facc = 0.5f * facc + xl[r];
    const v4f fm1 = facc;  // fwd[s0-1]
#pragma unroll
    for (int r = 0; r < C; ++r) {
        facc = 0.5f * facc + xa[r];
        xa[r] = facc;  // buffer now holds fwd
    }

    // ---- backward recurrence + combine + store ----
    v4f bacc = (v4f)0.0f;
#pragma unroll
    for (int r = K - 1; r >= 0; --r) bacc = 0.5f * bacc + xr[r];

    const bool interior = (s0 >= 32) && (s0 + C <= S - 32);
#pragma unroll
    for (int r = C - 1; r >= 0; --r) {
        const v4f f = xa[r];                         // fwd[i]
        const v4f fp = (r > 0) ? xa[r - 1] : fm1;    // fwd[i-1]
        const v4f xt = f - 0.5f * fp;                // recover x[i] exactly
        bacc = 0.5f * bacc + xt;                     // bwd[i]
        const int i = s0 + r;
        float rn = 0.25f;  // norm == 4 exactly for interior rows
        if (!interior) {
            rn = 1.0f / (4.0f - exp2f((float)(-i)) -
                         exp2f((float)(i - (S - 1))));
        }
        __builtin_nontemporal_store((f + bacc) * rn, &op[(size_t)i * HV]);
    }
}

extern "C" void kernel_launch(void* const* d_in, const int* in_sizes, int n_in,
                              void* d_out, int out_size, void* d_ws,
                              size_t ws_size, hipStream_t stream) {
    const v4f* x = (const v4f*)d_in[0];
    v4f* out = (v4f*)d_out;
    decay_kernel<<<dim3(NBLK), THREADS, 0, stream>>>(x, out);
}

// Round 3
// 240.609 us; speedup vs baseline: 1.2534x; 1.2534x over previous
//
#include <hip/hip_runtime.h>
#include <stdint.h>

// DecayModel: out[b,i,h] = (fwd[i] + bwd[i]) / norm[i], decay = 0.5
//   fwd[i] = sum_{k<=i} 0.5^{i-k} x[k],  bwd[i] = sum_{k>=i} 0.5^{k-i} x[k]
//   norm[i] = 4 - 2^{-i} - 2^{-(S-1-i)}   (== 4.0f exactly for interior i)
//
// R8 -> R9: LDS-ring streaming scan with zero-VGPR staging.
// R8's counters (VGPR=64, WRITE 292MB = 2.2x output, FETCH 184MB) showed the
// register tile SPILLED to scratch. Any VGPR-tile formulation either starves
// load ILP (R7) or spills (R8). Fix: stage x through LDS with
// global_load_lds (no VGPR cost, vmcnt-counted), 4-buffer ring of W=8-row
// subtiles, counted s_waitcnt vmcnt(8) that NEVER drains (T4). Each wave
// stages exactly the 64 columns it alone reads -> no barriers anywhere;
// vmcnt is the only synchronization. Register file holds only scan state
// (~60 VGPR). Per CU/iter: 64KB HBM (6400cy) vs ~2000cy VALU -> BW-bound.
// fwd carried exactly across chunk (12-tap halo init); bwd 12-tap lookahead
// from staged next subtiles (real data across chunk boundaries, zeroed past
// S). Numerics identical to R7. Occupancy 4 waves/CU is BY DESIGN (LDS
// 64KB/block, 2 blocks/CU): latency hiding comes from async DMA, not TLP.

constexpr int B = 16;
constexpr int S = 2048;
constexpr int HV = 256;        // v4f per full row (H = 1024 floats)
constexpr int C = 128;         // rows per chunk
constexpr int W = 8;           // subtile rows
constexpr int NT = C / W;      // 16 subtiles per chunk
constexpr int K = 12;          // truncation taps: 0.5^13*6sigma ~ 7e-4
constexpr int THREADS = 128;   // 2 waves; block covers half a row
constexpr int BH = 128;        // v4f columns per block
constexpr int NBUF = 4;        // LDS ring depth
constexpr int NCHUNK = S / C;  // 16
constexpr int NBLK = B * NCHUNK * (HV / BH);  // 512 blocks -> 2 per CU

typedef float v4f __attribute__((ext_vector_type(4)));

__device__ __forceinline__ void gload16(const v4f* g, v4f* l) {
    // HBM -> LDS direct, 16B/lane; LDS dest = wave-uniform base + lane*16.
    __builtin_amdgcn_global_load_lds(
        (const __attribute__((address_space(1))) uint32_t*)g,
        (__attribute__((address_space(3))) uint32_t*)l, 16, 0, 0);
}

template <int PH>
__device__ __forceinline__ void body(int n, int s0, int slim, bool edge,
                                     const v4f* __restrict__ xp,
                                     v4f* __restrict__ op, int tid, int wv,
                                     v4f (*lds)[W][BH], v4f& facc) {
    constexpr int bcur = PH & 3;        // subtile n
    constexpr int bnx1 = (PH + 1) & 3;  // subtile n+1 (lookahead)
    constexpr int bnx2 = (PH + 2) & 3;  // subtile n+2 (lookahead tail)
    constexpr int bprf = (PH + 3) & 3;  // prefetch target

    // ---- issue prefetch of subtile n+3 (subtiles 16,17 = right halo) ----
    if (n + 3 <= NT + 1) {
#pragma unroll
        for (int r = 0; r < W; ++r) {
            int srow = s0 + (n + 3) * W + r;
            srow = srow > S - 1 ? S - 1 : srow;  // clamp; zero-predicated tap
            gload16(xp + (size_t)srow * HV, &lds[bprf][r][wv * 64]);
        }
    }
    // Counted wait: newest 8 ops = the loads just issued; everything older
    // (subtile n+2's loads, prior stores) retired. Never drains to 0.
    asm volatile("s_waitcnt vmcnt(8)" ::: "memory");

    // ---- forward recurrence over subtile n (exact within chunk) ----
    const v4f fprev = facc;
    v4f f[W];
    v4f fa = facc;
#pragma unroll
    for (int r = 0; r < W; ++r) {
        fa = 0.5f * fa + lds[bcur][r][tid];
        f[r] = fa;
    }
    facc = fa;

    // ---- backward 12-tap lookahead init (rows past subtile end) ----
    v4f bacc = (v4f)0.0f;
#pragma unroll
    for (int j = K - 1; j >= 0; --j) {
        v4f t = (j < W) ? lds[bnx1][j][tid] : lds[bnx2][j - W][tid];
        if ((n + 1) * W + j >= slim) t = (v4f)0.0f;  // rows >= S contribute 0
        bacc = 0.5f * bacc + t;
    }

    // ---- backward march + combine + store ----
#pragma unroll
    for (int r = W - 1; r >= 0; --r) {
        const v4f fr = f[r];
        const v4f fm = r ? f[r - 1] : fprev;
        bacc = 0.5f * bacc + (fr - 0.5f * fm);  // recover x[i], extend bwd
        const int i = s0 + n * W + r;
        float rn = 0.25f;  // norm == 4.0f exactly for interior chunks
        if (edge)
            rn = 1.0f / (4.0f - exp2f((float)(-i)) -
                         exp2f((float)(i - (S - 1))));
        __builtin_nontemporal_store((fr + bacc) * rn, op + (size_t)i * HV);
    }
}

__global__ __launch_bounds__(THREADS, 1) void decay_kernel(
    const v4f* __restrict__ x, v4f* __restrict__ out) {
    __shared__ v4f lds[NBUF][W][BH];  // 4 * 8 * 128 * 16B = 64 KiB

    // Bijective XCD swizzle (512 % 8 == 0): each XCD gets 2 whole batches,
    // so chunk-boundary halo/lookahead overlap stays in one XCD's L2.
    const int bid = blockIdx.x;
    const int swz = (bid & 7) * (NBLK / 8) + (bid >> 3);
    const int h = swz & 1;                 // half-row
    const int cc = (swz >> 1) & (NCHUNK - 1);
    const int b = swz >> 5;                // batch
    const int s0 = cc * C;
    const int slim = S - s0;
    const bool edge = (cc == 0) | (cc == NCHUNK - 1);

    const int tid = threadIdx.x;
    const int wv = tid >> 6;

    const size_t colBase = (size_t)b * S * HV + (size_t)(h * BH) + tid;
    const v4f* __restrict__ xp = x + colBase;  // xp[s*HV] = x[b, s, col]
    v4f* __restrict__ op = out + colBase;

    // ---- prologue: left halo (12 rows) + subtiles 0,1 in one burst ----
#pragma unroll
    for (int r = 4; r < W; ++r) {  // subtile -2 rows 4..7 -> buf2
        int srow = s0 - 2 * W + r;
        srow = srow < 0 ? 0 : srow;
        gload16(xp + (size_t)srow * HV, &lds[2][r][wv * 64]);
    }
#pragma unroll
    for (int r = 0; r < W; ++r) {  // subtile -1 -> buf3
        int srow = s0 - W + r;
        srow = srow < 0 ? 0 : srow;
        gload16(xp + (size_t)srow * HV, &lds[3][r][wv * 64]);
    }
#pragma unroll
    for (int r = 0; r < W; ++r)    // subtile 0 -> buf0
        gload16(xp + (size_t)(s0 + r) * HV, &lds[0][r][wv * 64]);
#pragma unroll
    for (int r = 0; r < W; ++r)    // subtile 1 -> buf1
        gload16(xp + (size_t)(s0 + W + r) * HV, &lds[1][r][wv * 64]);

    // oldest 12 (halo) done; subtiles 0,1 still in flight
    asm volatile("s_waitcnt vmcnt(16)" ::: "memory");

    // fwd carry-in: 12-tap truncated scan over the left halo
    v4f facc = (v4f)0.0f;
    if (s0 > 0) {
#pragma unroll
        for (int r = 4; r < W; ++r) facc = 0.5f * facc + lds[2][r][tid];
#pragma unroll
        for (int r = 0; r < W; ++r) facc = 0.5f * facc + lds[3][r][tid];
        // halo ds_reads must complete before buf2 is overwritten below
        asm volatile("s_waitcnt lgkmcnt(0)" ::: "memory");
    }
#pragma unroll
    for (int r = 0; r < W; ++r)    // subtile 2 -> buf2 (halo consumed)
        gload16(xp + (size_t)(s0 + 2 * W + r) * HV, &lds[2][r][wv * 64]);

    // ---- main loop: 16 subtiles, unrolled x4 for static ring indices ----
    for (int t = 0; t < NT; t += 4) {
        body<0>(t + 0, s0, slim, edge, xp, op, tid, wv, lds, facc);
        body<1>(t + 1, s0, slim, edge, xp, op, tid, wv, lds, facc);
        body<2>(t + 2, s0, slim, edge, xp, op, tid, wv, lds, facc);
        body<3>(t + 3, s0, slim, edge, xp, op, tid, wv, lds, facc);
    }
}

extern "C" void kernel_launch(void* const* d_in, const int* in_sizes, int n_in,
                              void* d_out, int out_size, void* d_ws,
                              size_t ws_size, hipStream_t stream) {
    const v4f* x = (const v4f*)d_in[0];
    v4f* out = (v4f*)d_out;
    decay_kernel<<<dim3(NBLK), THREADS, 0, stream>>>(x, out);
}

// Round 5
// 239.179 us; speedup vs baseline: 1.2609x; 1.0060x over previous
//
#include <hip/hip_runtime.h>

// DecayModel: out[b,i,h] = (fwd[i] + bwd[i]) / norm[i], decay = 0.5
//   fwd[i] = sum_{k<=i} 0.5^{i-k} x[k],  bwd[i] = sum_{k>=i} 0.5^{k-i} x[k]
//   norm[i] = 4 - 2^{-i} - 2^{-(S-1-i)}   (== 4.0f exactly for interior i)
//
// R10 resubmit (R11): broker timeout, no signal -- theory unchanged.
// High-TLP flat tile with a register tile that FITS.
// Post-mortem of the plateau (R6 85us / R7 85us / R9 93us, all ~2.3-2.5
// TB/s): every low-occupancy ILP design stalls ~14k cyc per iteration --
// R9's vmcnt(8) secretly waits on the previous iteration's nontemporal
// stores (they sit between load batches in the in-order vmcnt queue), and
// lookahead loaded 1 iter ahead gives <1 HBM latency of slack. Rather than
// keep fighting waitcnt coupling, saturate with waves: at 16 waves/CU the
// per-wave in-flight requirement is only ~575B (9.2KB latency-BW product
// per CU), robust to any compiler schedule.
// R8 tried this and SPILLED (v4f tile = 224 VGPR > 128 cap; WRITE 292MB).
// Fix: float2 columns -> tile = (16+12+12) x float2 = 80 VGPR + ~30 working
// < 128 cap of __launch_bounds__(256,4). Grid 4096 blocks = 4 blocks/CU,
// 16 waves/CU. Halo read amplification 2.5x is L3-absorbed (input 128MB <
// 256MB L3; R9 FETCH=79MB proved re-reads never reach HBM). Nontemporal
// stores keep output out of L2/L3 so input stays cache-resident.
// Verify in counters: VGPR ~104-120 (64 would mean capped+spilled),
// WRITE ~131MB (no spill), occupancy ~45%.

constexpr int B = 16;
constexpr int S = 2048;
constexpr int H = 1024;
constexpr int H2 = H / 2;        // 512 float2 per row
constexpr int C = 16;            // tile rows per block
constexpr int K = 12;            // halo taps: 0.5^13 * 6sigma ~ 7e-4 << tol
constexpr int THREADS = 256;     // 4 waves; each thread owns one float2 col
constexpr int CG = H2 / THREADS; // 2 column groups per row
constexpr int NCH = S / C;       // 128 chunks
constexpr int NBLK = B * NCH * CG;  // 4096 blocks -> 4 resident per CU
constexpr int NXCD = 8;

typedef float v2f __attribute__((ext_vector_type(2)));

__global__ __launch_bounds__(THREADS, 4) void decay_kernel(
    const v2f* __restrict__ x, v2f* __restrict__ out) {
    // Bijective XCD swizzle (NBLK % 8 == 0). Decode puts colgroup fastest,
    // chunk next -> each XCD owns 2 whole batches; chunk-neighbors (sharing
    // 12-row halos) stay in one XCD's L2.
    const int bid = blockIdx.x;
    const int swz = (bid & (NXCD - 1)) * (NBLK / NXCD) + (bid >> 3);
    const int cg = swz & (CG - 1);
    const int chunk = (swz >> 1) & (NCH - 1);
    const int b = swz >> 8;
    const int s0 = chunk * C;

    const size_t colBase =
        (size_t)b * S * H2 + (size_t)cg * THREADS + threadIdx.x;
    const v2f* __restrict__ xp = x + colBase;  // xp[s*H2] = x[b, s, col]
    v2f* __restrict__ op = out + colBase;

    // ---- issue all 40 row loads up front (80 VGPR of destinations: the
    //      whole burst fits the register budget, unlike R8) ----
    v2f xl[K], xa[C], xr[K];
#pragma unroll
    for (int r = 0; r < K; ++r) {
        const int s = s0 - K + r;
        xl[r] = xp[(size_t)(s < 0 ? 0 : s) * H2];
    }
#pragma unroll
    for (int r = 0; r < C; ++r) xa[r] = xp[(size_t)(s0 + r) * H2];
#pragma unroll
    for (int r = 0; r < K; ++r) {
        const int s = s0 + C + r;
        xr[r] = xp[(size_t)(s > S - 1 ? S - 1 : s) * H2];
    }
    // zero out-of-range halo rows (wave-uniform; only first/last chunks)
    if (chunk == 0) {
#pragma unroll
        for (int r = 0; r < K; ++r) xl[r] = (v2f)0.0f;
    }
    if (chunk == NCH - 1) {
#pragma unroll
        for (int r = 0; r < K; ++r) xr[r] = (v2f)0.0f;
    }

    // ---- forward recurrence (K-tap truncated carry-in, exact in tile) ----
    v2f facc = (v2f)0.0f;
#pragma unroll
    for (int r = 0; r < K; ++r) facc = 0.5f * facc + xl[r];
    const v2f fm1 = facc;  // fwd[s0-1]
#pragma unroll
    for (int r = 0; r < C; ++r) {
        facc = 0.5f * facc + xa[r];
        xa[r] = facc;  // buffer now holds fwd
    }

    // ---- backward recurrence + combine + store ----
    v2f bacc = (v2f)0.0f;
#pragma unroll
    for (int r = K - 1; r >= 0; --r) bacc = 0.5f * bacc + xr[r];

    const bool interior = (s0 >= 32) && (s0 + C <= S - 32);
#pragma unroll
    for (int r = C - 1; r >= 0; --r) {
        const v2f f = xa[r];                       // fwd[i]
        const v2f fp = (r > 0) ? xa[r - 1] : fm1;  // fwd[i-1]
        bacc = 0.5f * bacc + (f - 0.5f * fp);      // recover x[i], extend bwd
        const int i = s0 + r;
        float rn = 0.25f;  // norm == 4.0f exactly for interior rows
        if (!interior) {
            rn = 1.0f / (4.0f - exp2f((float)(-i)) -
                         exp2f((float)(i - (S - 1))));
        }
        __builtin_nontemporal_store((f + bacc) * rn, op + (size_t)i * H2);
    }
}

extern "C" void kernel_launch(void* const* d_in, const int* in_sizes, int n_in,
                              void* d_out, int out_size, void* d_ws,
                              size_t ws_size, hipStream_t stream) {
    const v2f* x = (const v2f*)d_in[0];
    v2f* out = (v2f*)d_out;
    decay_kernel<<<dim3(NBLK), THREADS, 0, stream>>>(x, out);
}

// Round 7
// 238.546 us; speedup vs baseline: 1.2642x; 1.0027x over previous
//
#include <hip/hip_runtime.h>

// DecayModel: out[b,i,h] = (fwd[i] + bwd[i]) / norm[i], decay = 0.5
//   fwd[i] = sum_{k<=i} 0.5^{i-k} x[k],  bwd[i] = sum_{k>=i} 0.5^{k-i} x[k]
//   norm[i] = 4 - 2^{-i} - 2^{-(S-1-i)}   (== 4.0f exactly for interior i)
//
// R12 -> R13: force the 40-load burst with sched_barrier(0), not inline asm.
// R12's asm failed to compile (clang put the "s"-constrained 64-bit base in
// a VGPR pair -> invalid saddr operand). Same goal, supported mechanism:
// R11 evidence (VGPR=48 @ 46% occupancy, 2.39 TB/s, FETCH 66MB) showed
// hipcc sank every load to its use -> depth-1 latency chains; 15 waves/CU
// x 512B = 7.7KB in flight per CU vs ~15KB needed at ~600ns mixed L3/HBM
// latency -> exactly the observed ~2.4 TB/s plateau (R6/R7/R9/R11).
// __builtin_amdgcn_sched_barrier(0) placed between the load burst and ALL
// uses: loads cannot sink past it, so regalloc must keep the 40 v2f
// destinations (80 VGPR) live -> ~20KB in flight per wave, 16 waves/CU.
// Everything else identical to the verified R11 kernel (isolates the
// burst-forcing in the counter delta).
// Verify: VGPR ~100-120 (48 again = fence failed), WRITE ~131MB (no
// spill), occupancy ~40-46%.

constexpr int B = 16;
constexpr int S = 2048;
constexpr int H = 1024;
constexpr int H2 = H / 2;        // 512 float2 per row
constexpr int C = 16;            // tile rows per block
constexpr int K = 12;            // halo taps: 0.5^13 * 6sigma ~ 7e-4 << tol
constexpr int THREADS = 256;     // 4 waves; each thread owns one float2 col
constexpr int CG = H2 / THREADS; // 2 column groups per row
constexpr int NCH = S / C;       // 128 chunks
constexpr int NBLK = B * NCH * CG;  // 4096 blocks -> 4 resident per CU
constexpr int NXCD = 8;

typedef float v2f __attribute__((ext_vector_type(2)));

__global__ __launch_bounds__(THREADS, 4) void decay_kernel(
    const v2f* __restrict__ x, v2f* __restrict__ out) {
    // Bijective XCD swizzle (NBLK % 8 == 0): each XCD owns 2 whole batches;
    // chunk-neighbors (sharing 12-row halos) stay in one XCD's L2.
    const int bid = blockIdx.x;
    const int swz = (bid & (NXCD - 1)) * (NBLK / NXCD) + (bid >> 3);
    const int cg = swz & (CG - 1);
    const int chunk = (swz >> 1) & (NCH - 1);
    const int b = swz >> 8;
    const int s0 = chunk * C;

    const size_t colBase =
        (size_t)b * S * H2 + (size_t)cg * THREADS + threadIdx.x;
    const v2f* __restrict__ xp = x + colBase;  // xp[s*H2] = x[b, s, col]
    v2f* __restrict__ op = out + colBase;

    // ---- issue all 40 row loads; the sched_barrier below pins them as a
    //      burst (no sinking to uses), forcing 80 VGPRs of dests live ----
    v2f xl[K], xa[C], xr[K];
#pragma unroll
    for (int r = 0; r < K; ++r) {
        const int s = s0 - K + r;
        xl[r] = xp[(size_t)(s < 0 ? 0 : s) * H2];
    }
#pragma unroll
    for (int r = 0; r < C; ++r) xa[r] = xp[(size_t)(s0 + r) * H2];
#pragma unroll
    for (int r = 0; r < K; ++r) {
        const int s = s0 + C + r;
        xr[r] = xp[(size_t)(s > S - 1 ? S - 1 : s) * H2];
    }

    // compile-time scheduling fence: no instruction may cross. All 40 loads
    // are issued above; every use is below.
    __builtin_amdgcn_sched_barrier(0);

    // zero out-of-range halo rows (wave-uniform; only first/last chunks)
    if (chunk == 0) {
#pragma unroll
        for (int r = 0; r < K; ++r) xl[r] = (v2f)0.0f;
    }
    if (chunk == NCH - 1) {
#pragma unroll
        for (int r = 0; r < K; ++r) xr[r] = (v2f)0.0f;
    }

    // ---- forward recurrence (K-tap truncated carry-in, exact in tile) ----
    v2f facc = (v2f)0.0f;
#pragma unroll
    for (int r = 0; r < K; ++r) facc = 0.5f * facc + xl[r];
    const v2f fm1 = facc;  // fwd[s0-1]
#pragma unroll
    for (int r = 0; r < C; ++r) {
        facc = 0.5f * facc + xa[r];
        xa[r] = facc;  // buffer now holds fwd
    }

    // ---- backward recurrence + combine + store ----
    v2f bacc = (v2f)0.0f;
#pragma unroll
    for (int r = K - 1; r >= 0; --r) bacc = 0.5f * bacc + xr[r];

    const bool interior = (s0 >= 32) && (s0 + C <= S - 32);
#pragma unroll
    for (int r = C - 1; r >= 0; --r) {
        const v2f f = xa[r];                       // fwd[i]
        const v2f fp = (r > 0) ? xa[r - 1] : fm1;  // fwd[i-1]
        bacc = 0.5f * bacc + (f - 0.5f * fp);      // recover x[i], extend bwd
        const int i = s0 + r;
        float rn = 0.25f;  // norm == 4.0f exactly for interior rows
        if (!interior) {
            rn = 1.0f / (4.0f - exp2f((float)(-i)) -
                         exp2f((float)(i - (S - 1))));
        }
        __builtin_nontemporal_store((f + bacc) * rn, op + (size_t)i * H2);
    }
}

extern "C" void kernel_launch(void* const* d_in, const int* in_sizes, int n_in,
                              void* d_out, int out_size, void* d_ws,
                              size_t ws_size, hipStream_t stream) {
    const v2f* x = (const v2f*)d_in[0];
    v2f* out = (v2f*)d_out;
    decay_kernel<<<dim3(NBLK), THREADS, 0, stream>>>(x, out);
}